// Round 3
// baseline (1431.873 us; speedup 1.0000x reference)
//
#include <hip/hip_runtime.h>

// out[r,f] = bias[f] + sum_{i: rows[i]==r} value[i] * weight[cols[i], f]
// Pipeline: per-chunk histograms (kA) -> reduce (kB1) -> fused scan + offsets
// (kB_off) -> atomic-free coarse bin (kC) -> fine bin with 64-wide window
// keys (kD) -> atomic-accumulate consumer (k_spmm7).
// R9 post-mortem: atomicAdd(float) on extern __shared__ lost addrspace(3) ->
// flat CAS loop through the LDS aperture (21x slower). R10: raw inline-asm
// ds_add_f32 — but FAILED (absmax 0.116): the waitcnt pass can't see
// inline-asm DS ops, so __syncthreads emitted no lgkmcnt(0) drain and the
// epilogue read acc while ds_adds were in flight. R11: explicit per-wave
// "s_waitcnt lgkmcnt(0)" + sched_barrier before the final __syncthreads.
//
// pair pack (u64): val[63:32] | fine[29:20] | lr[19:13] | col[12:0]

#define NBF 1024
#define DMAX 128     // lr 7 bits => d <= 128 (n <= 131072)
#define CH 4096      // binning chunk (kA, kC, kD)
#define SP_T 512
#define APAD 65      // acc row stride (floats)

__device__ __forceinline__ void ds_fadd(float* p, float v) {
    unsigned a = (unsigned)(unsigned long long)p;  // LDS byte offset (aperture 2^32-aligned)
    asm volatile("ds_add_f32 %0, %1" :: "v"(a), "v"(v) : "memory");
}

__global__ void k_zero1024(int* __restrict__ p) { p[threadIdx.x] = 0; }

// Per-chunk fine (1024) + coarse (64) histograms, per-block writes.
// Chunk mapping MUST match kC_bin1.
__global__ __launch_bounds__(512) void kA_hist(const int* __restrict__ rows, int nnz,
        unsigned M, int S, int* __restrict__ hist2dF, int* __restrict__ hist2dC) {
    __shared__ int h[NBF];
    int t = threadIdx.x, blk = blockIdx.x;
    long long base = (long long)blk * CH;
    int count = (int)min((long long)CH, (long long)nnz - base);
    h[t] = 0; h[t + 512] = 0;
    __syncthreads();
#pragma unroll
    for (int k = 0; k < 8; ++k) {
        int i = t + (k << 9);
        if (i < count) {
            unsigned r = (unsigned)rows[base + i];
            int f = (int)(((unsigned long long)r * M) >> S);
            atomicAdd(&h[f], 1);
        }
    }
    __syncthreads();
    hist2dF[blk * NBF + t] = h[t];
    hist2dF[blk * NBF + 512 + t] = h[t + 512];
    if (t < 64) {
        int s = 0;
#pragma unroll
        for (int j = 0; j < 16; ++j) s += h[(t << 4) + j];
        hist2dC[(blk << 6) + t] = s;
    }
}

// Parallel column-reduce hist2dF -> gcnt.
__global__ __launch_bounds__(1024) void kB1_reduce(const int* __restrict__ hist2dF,
        int nChunks, int* __restrict__ gcnt) {
    int t = threadIdx.x;
    int s = 0;
    for (int b = blockIdx.x; b < nChunks; b += gridDim.x) s += hist2dF[b * NBF + t];
    if (s) atomicAdd(&gcnt[t], s);
}

// Fused: every block scans gcnt (cheap, redundant); block 0 emits fineBase +
// cursorF; if doOff, block c also scans hist2dC[:,c] over the chunk axis.
__global__ __launch_bounds__(1024) void kB_off(const int* __restrict__ gcnt,
        const int* __restrict__ hist2dC, int nChunks, int* __restrict__ fineBase,
        int* __restrict__ cursorF, int* __restrict__ blockOffC, int doOff) {
    __shared__ int sE[NBF];
    __shared__ int wsum[16];
    __shared__ int totalSh;
    int t = threadIdx.x, lane = t & 63, wv = t >> 6;
    int v = gcnt[t];
    int x = v;
#pragma unroll
    for (int off = 1; off < 64; off <<= 1) {
        int y = __shfl_up(x, off, 64);
        if (lane >= off) x += y;
    }
    if (lane == 63) wsum[wv] = x;
    __syncthreads();
    if (t < 16) {
        int s = wsum[t], xs = s;
#pragma unroll
        for (int off = 1; off < 16; off <<= 1) {
            int y = __shfl_up(xs, off, 16);
            if (t >= off) xs += y;
        }
        wsum[t] = xs - s;
    }
    __syncthreads();
    int incl = x + wsum[wv], excl = incl - v;
    sE[t] = excl;
    if (blockIdx.x == 0) {
        fineBase[t] = excl;
        cursorF[t] = excl;
        if (t == NBF - 1) fineBase[NBF] = incl;
    }
    __syncthreads();
    if (!doOff) return;
    int c = blockIdx.x;
    int carry = sE[c << 4];
    for (int b2 = 0; b2 < nChunks; b2 += 1024) {
        int idx = b2 + t;
        int hv = (idx < nChunks) ? hist2dC[(idx << 6) + c] : 0;
        int hx = hv;
#pragma unroll
        for (int off = 1; off < 64; off <<= 1) {
            int y = __shfl_up(hx, off, 64);
            if (lane >= off) hx += y;
        }
        if (lane == 63) wsum[wv] = hx;
        __syncthreads();
        if (t < 16) {
            int s = wsum[t], xs = s;
#pragma unroll
            for (int off = 1; off < 16; off <<= 1) {
                int y = __shfl_up(xs, off, 16);
                if (t >= off) xs += y;
            }
            wsum[t] = xs - s;
        }
        __syncthreads();
        int hincl = hx + wsum[wv];
        if (idx < nChunks) blockOffC[(idx << 6) + c] = carry + hincl - hv;
        if (t == 1023) totalSh = hincl;
        __syncthreads();
        carry += totalSh;
    }
}

// Path3 fallback: grid-stride fine histogram with global atomics.
__global__ void k_ghist(const int* __restrict__ rows, int nnz, unsigned M, int S,
                        int* __restrict__ gcnt) {
    __shared__ int h[NBF];
    int t = threadIdx.x;
    for (int i = t; i < NBF; i += blockDim.x) h[i] = 0;
    __syncthreads();
    for (int i = blockIdx.x * blockDim.x + t; i < nnz; i += gridDim.x * blockDim.x) {
        unsigned r = (unsigned)rows[i];
        int f = (int)(((unsigned long long)r * M) >> S);
        atomicAdd(&h[f], 1);
    }
    __syncthreads();
    for (int i = t; i < NBF; i += blockDim.x)
        if (h[i]) atomicAdd(&gcnt[i], h[i]);
}

// Coarse bin, atomic-free: dest base from precomputed blockOffC. Runs ~512 B.
__global__ __launch_bounds__(512) void kC_bin1(const int* __restrict__ rows,
        const int* __restrict__ cols, const float* __restrict__ vals, int nnz,
        unsigned M, int S, int d, const int* __restrict__ blockOffC,
        unsigned long long* __restrict__ pairs1) {
    __shared__ unsigned long long stage[CH];  // 32 KB
    __shared__ int histC[64], scC[64], adjC[64];
    int t = threadIdx.x, blk = blockIdx.x;
    long long base = (long long)blk * CH;
    int count = (int)min((long long)CH, (long long)nnz - base);
    if (t < 64) histC[t] = 0;
    __syncthreads();
    int cs8[8], rk8[8];
    unsigned long long pk8[8];
#pragma unroll
    for (int k = 0; k < 8; ++k) {
        int i = t + (k << 9);
        cs8[k] = -1;
        if (i < count) {
            unsigned r = (unsigned)rows[base + i];
            int c = cols[base + i];
            float v = vals[base + i];
            int f = (int)(((unsigned long long)r * M) >> S);
            int lr = (int)r - f * d;
            int cs = f >> 4;
            cs8[k] = cs;
            rk8[k] = atomicAdd(&histC[cs], 1);
            pk8[k] = ((unsigned long long)__float_as_uint(v) << 32) |
                     ((unsigned)f << 20) | ((unsigned)lr << 13) | (unsigned)c;
        }
    }
    __syncthreads();
    if (t < 64) {
        int v = histC[t], x = v;
#pragma unroll
        for (int off = 1; off < 64; off <<= 1) {
            int y = __shfl_up(x, off, 64);
            if (t >= off) x += y;
        }
        scC[t] = x;
        adjC[t] = blockOffC[(blk << 6) + t] - (x - v);
    }
    __syncthreads();
#pragma unroll
    for (int k = 0; k < 8; ++k)
        if (cs8[k] >= 0) stage[(scC[cs8[k]] - histC[cs8[k]]) + rk8[k]] = pk8[k];
    __syncthreads();
    for (int i = t; i < count; i += 512) {
        unsigned long long p = stage[i];
        int cs = (int)((p >> 24) & 63);
        pairs1[adjC[cs] + i] = p;
    }
}

// Fine bin from coarse-sorted pairs. Window base f0 = coarse-aligned floor of
// the FIRST element's fine id: coarse-sorted order guarantees every fine id
// in the chunk is >= cFirst*16 (fine order WITHIN a coarse run is arbitrary —
// taking fFirst itself was R8's OOB crash). Span check: fLast < f0+64
// (chunk spans <= 4 coarse buckets; typically <= 2 since runs ~62k >> 4096).
__global__ __launch_bounds__(1024) void kD_bin2(const unsigned long long* __restrict__ pairs1,
        int nnz, int* __restrict__ cursorF, unsigned long long* __restrict__ pairs2) {
    __shared__ unsigned long long stage[CH];  // 32 KB
    __shared__ int histW[64], scW[64], adjW[64];
    __shared__ int f0sh;
    int t = threadIdx.x;
    long long base = (long long)blockIdx.x * CH;
    int count = (int)min((long long)CH, (long long)nnz - base);
    if (t == 0) {
        int fFirst = (int)((pairs1[base] >> 20) & 1023);
        int fLast  = (int)((pairs1[base + count - 1] >> 20) & 1023);
        int f0 = (fFirst >> 4) << 4;          // coarse-aligned lower bound
        f0sh = (fLast < f0 + 64) ? f0 : -1;
    }
    if (t < 64) histW[t] = 0;
    __syncthreads();
    int f0 = f0sh;
    if (f0 < 0) {
        // slow path: per-pair scatter (correct for arbitrary span)
#pragma unroll
        for (int k = 0; k < 4; ++k) {
            int i = t + (k << 10);
            if (i < count) {
                unsigned long long p = pairs1[base + i];
                int f = (int)((p >> 20) & 1023);
                int pos = atomicAdd(&cursorF[f], 1);
                pairs2[pos] = p;
            }
        }
        return;
    }
    int k4[4], rk4[4];
    unsigned long long pk4[4];
#pragma unroll
    for (int k = 0; k < 4; ++k) {
        int i = t + (k << 10);
        k4[k] = -1;
        if (i < count) {
            unsigned long long p = pairs1[base + i];
            int kf = (int)((p >> 20) & 1023) - f0;
            k4[k] = kf;
            rk4[k] = atomicAdd(&histW[kf], 1);
            pk4[k] = p;
        }
    }
    __syncthreads();
    if (t < 64) {  // wave 0: 64-wide shfl scan
        int v = histW[t], x = v;
#pragma unroll
        for (int off = 1; off < 64; off <<= 1) {
            int y = __shfl_up(x, off, 64);
            if (t >= off) x += y;
        }
        scW[t] = x;
        if (v > 0) {
            int g = atomicAdd(&cursorF[f0 + t], v);
            adjW[t] = g - (x - v);
        }
    }
    __syncthreads();
#pragma unroll
    for (int k = 0; k < 4; ++k)
        if (k4[k] >= 0) stage[(scW[k4[k]] - histW[k4[k]]) + rk4[k]] = pk4[k];
    __syncthreads();
    for (int i = t; i < count; i += 1024) {
        unsigned long long p = stage[i];
        int kf = (int)((p >> 20) & 1023) - f0;
        pairs2[adjW[kf] + i] = p;
    }
}

// Fallback direct fine bin: source -> fine buckets, cursorF atomics.
__global__ __launch_bounds__(1024) void k_bin_direct(const int* __restrict__ rows,
        const int* __restrict__ cols, const float* __restrict__ vals, int nnz,
        unsigned M, int S, int d, int* __restrict__ cursorF,
        unsigned long long* __restrict__ pairs1) {
    __shared__ unsigned long long stage[CH];
    __shared__ int histF[NBF], scF[NBF], adjF[NBF];
    __shared__ int wsum[16];
    int t = threadIdx.x, lane = t & 63, wv = t >> 6;
    long long base = (long long)blockIdx.x * CH;
    int count = (int)min((long long)CH, (long long)nnz - base);
    histF[t] = 0;
    __syncthreads();
    int f4[4], rk4[4];
    unsigned long long pk4[4];
#pragma unroll
    for (int k = 0; k < 4; ++k) {
        int i = t + (k << 10);
        f4[k] = -1;
        if (i < count) {
            unsigned r = (unsigned)rows[base + i];
            int c = cols[base + i];
            float vv = vals[base + i];
            int f = (int)(((unsigned long long)r * M) >> S);
            int lr = (int)r - f * d;
            f4[k] = f;
            rk4[k] = atomicAdd(&histF[f], 1);
            pk4[k] = ((unsigned long long)__float_as_uint(vv) << 32) |
                     ((unsigned)f << 20) | ((unsigned)lr << 13) | (unsigned)c;
        }
    }
    __syncthreads();
    int v = histF[t], x = v;
#pragma unroll
    for (int off = 1; off < 64; off <<= 1) {
        int y = __shfl_up(x, off, 64);
        if (lane >= off) x += y;
    }
    if (lane == 63) wsum[wv] = x;
    __syncthreads();
    if (t < 16) {
        int s = wsum[t], xs = s;
#pragma unroll
        for (int off = 1; off < 16; off <<= 1) {
            int y = __shfl_up(xs, off, 16);
            if (t >= off) xs += y;
        }
        wsum[t] = xs - s;
    }
    __syncthreads();
    int incl = x + wsum[wv];
    scF[t] = incl;
    if (v > 0) {
        int g = atomicAdd(&cursorF[t], v);
        adjF[t] = g - (incl - v);
    }
    __syncthreads();
#pragma unroll
    for (int k = 0; k < 4; ++k)
        if (f4[k] >= 0) stage[(scF[f4[k]] - histF[f4[k]]) + rk4[k]] = pk4[k];
    __syncthreads();
    for (int i = t; i < count; i += 1024) {
        unsigned long long p = stage[i];
        int f = (int)((p >> 20) & 1023);
        pairs1[adjF[f] + i] = p;
    }
}

// Consumer v3: one block per fine bucket. No sort, no stage, no main-loop
// barriers. Each 16-lane group streams 4 consecutive pairs per iteration
// (broadcast global reads), issues 4 independent dwordx4 weight loads, and
// accumulates via inline-asm ds_add_f32 (fire-and-forget). Acc layout:
// row*APAD + j*16 + fq so the 16 lanes of a group hit 16 consecutive banks
// per instruction. CRITICAL: explicit per-wave s_waitcnt lgkmcnt(0) before
// the final barrier — the compiler cannot see inline-asm DS ops, so
// __syncthreads alone does NOT drain them (R10's 0.116 absmax failure).
__global__ __launch_bounds__(SP_T, 8) void k_spmm7(
        const unsigned long long* __restrict__ pairs, const int* __restrict__ fineBase,
        const float* __restrict__ weight, const float* __restrict__ bias,
        float* __restrict__ out, int d, int n) {
    extern __shared__ float acc[];             // d*APAD floats (25.5 KB @ d=98)
    int b = blockIdx.x, t = threadIdx.x;
    int row0 = b * d;
    if (row0 >= n) return;
    int nrows = min(d, n - row0);
    int start = fineBase[b], end = fineBase[b + 1];

    for (int i = t; i < nrows * APAD; i += SP_T) acc[i] = 0.0f;
    __syncthreads();

    int g = t >> 4, fq = t & 15;
    const int fo = fq << 2;
    for (int ib = start + (g << 2); ib < end; ib += (SP_T >> 4) << 2) {
        int m = end - ib;  // >= 1
        unsigned long long p0 = pairs[ib];
        unsigned long long p1 = (m > 1) ? pairs[ib + 1] : 0ull;
        unsigned long long p2 = (m > 2) ? pairs[ib + 2] : 0ull;
        unsigned long long p3 = (m > 3) ? pairs[ib + 3] : 0ull;
        const float4 w0 = *(const float4*)(weight + (((int)(p0 & 8191)) << 6) + fo);
        const float4 w1 = *(const float4*)(weight + (((int)(p1 & 8191)) << 6) + fo);
        const float4 w2 = *(const float4*)(weight + (((int)(p2 & 8191)) << 6) + fo);
        const float4 w3 = *(const float4*)(weight + (((int)(p3 & 8191)) << 6) + fo);
        float v0 = __uint_as_float((unsigned)(p0 >> 32));
        float v1 = __uint_as_float((unsigned)(p1 >> 32));
        float v2 = __uint_as_float((unsigned)(p2 >> 32));
        float v3 = __uint_as_float((unsigned)(p3 >> 32));
        float* a0 = acc + (int)((p0 >> 13) & 127) * APAD + fq;
        float* a1 = acc + (int)((p1 >> 13) & 127) * APAD + fq;
        float* a2 = acc + (int)((p2 >> 13) & 127) * APAD + fq;
        float* a3 = acc + (int)((p3 >> 13) & 127) * APAD + fq;
        // padded pairs (p==0) contribute v=0 -> harmless +0.0f to row 0
        ds_fadd(a0 +  0, v0 * w0.x); ds_fadd(a0 + 16, v0 * w0.y);
        ds_fadd(a0 + 32, v0 * w0.z); ds_fadd(a0 + 48, v0 * w0.w);
        ds_fadd(a1 +  0, v1 * w1.x); ds_fadd(a1 + 16, v1 * w1.y);
        ds_fadd(a1 + 32, v1 * w1.z); ds_fadd(a1 + 48, v1 * w1.w);
        ds_fadd(a2 +  0, v2 * w2.x); ds_fadd(a2 + 16, v2 * w2.y);
        ds_fadd(a2 + 32, v2 * w2.z); ds_fadd(a2 + 48, v2 * w2.w);
        ds_fadd(a3 +  0, v3 * w3.x); ds_fadd(a3 + 16, v3 * w3.y);
        ds_fadd(a3 + 32, v3 * w3.z); ds_fadd(a3 + 48, v3 * w3.w);
    }

    // Drain OUR inline-asm ds_adds (invisible to the compiler's waitcnt
    // scoreboard), then barrier so every wave's updates are visible.
    asm volatile("s_waitcnt lgkmcnt(0)" ::: "memory");
    __builtin_amdgcn_sched_barrier(0);
    __syncthreads();

    // feature f = fq*4 + j stored at j*16 + fq  =>  acc[r*APAD + (f&3)*16 + (f>>2)]
    for (int i = t; i < (nrows << 6); i += SP_T) {
        int r = i >> 6, f = i & 63;
        out[((long long)row0 << 6) + i] = acc[r * APAD + ((f & 3) << 4) + (f >> 2)] + bias[f];
    }
}

extern "C" void kernel_launch(void* const* d_in, const int* in_sizes, int n_in,
                              void* d_out, int out_size, void* d_ws, size_t ws_size,
                              hipStream_t stream) {
    const int*   index  = (const int*)d_in[0];
    const float* value  = (const float*)d_in[1];
    const float* weight = (const float*)d_in[3];
    const float* bias   = (const float*)d_in[4];
    float*       out    = (float*)d_out;

    int nnz = in_sizes[0] / 2;
    int n   = out_size / 64;
    const int* rows = index;
    const int* cols = index + nnz;

    int d = (n + NBF - 1) / NBF;  // 98 for n=100000 (<= DMAX)
    unsigned M = 0;
    int S = 0;
    for (S = 20; S <= 40; ++S) {
        unsigned long long m = ((1ull << S) + (unsigned)d - 1) / (unsigned)d;
        unsigned long long e = m * (unsigned long long)d - (1ull << S);
        if (m <= 0xffffffffull && e * (unsigned long long)(n > 0 ? n - 1 : 0) < (1ull << S)) {
            M = (unsigned)m;
            break;
        }
    }

    int nChunks = (nnz + CH - 1) / CH;
    char* ws = (char*)d_ws;
    int* fineBase = (int*)ws;                 // 8 KB reserved
    int* cursorF  = (int*)(ws + (8 << 10));   // 4 KB
    int* gcnt     = (int*)(ws + (12 << 10));  // 4 KB
    size_t offC = 64 << 10;
    size_t szC  = (((size_t)nChunks * 64 * 4) + 255) & ~(size_t)255;
    size_t offO = offC + szC;                 // blockOffC
    size_t offF = offO + szC;                 // hist2dF
    size_t szF  = (((size_t)nChunks * NBF * 4) + 255) & ~(size_t)255;
    size_t offP1 = offF + szF;
    size_t szP   = (((size_t)nnz * 8) + 255) & ~(size_t)255;
    size_t offP2 = offP1 + szP;
    int* hist2dC   = (int*)(ws + offC);
    int* blockOffC = (int*)(ws + offO);
    int* hist2dF   = (int*)(ws + offF);
    unsigned long long* pairs1 = (unsigned long long*)(ws + offP1);
    unsigned long long* pairs2 = (unsigned long long*)(ws + offP2);
    unsigned long long* pairs3 = (unsigned long long*)(ws + offC);  // path3 overlay

    bool two = ws_size >= offP2 + szP;
    bool dir = !two && ws_size >= offP1 + szP;

    k_zero1024<<<1, 1024, 0, stream>>>(gcnt);
    size_t smem = (size_t)d * APAD * sizeof(float);
    if (two || dir) {
        kA_hist<<<nChunks, 512, 0, stream>>>(rows, nnz, M, S, hist2dF, hist2dC);
        kB1_reduce<<<64, 1024, 0, stream>>>(hist2dF, nChunks, gcnt);
        if (two) {
            kB_off<<<64, 1024, 0, stream>>>(gcnt, hist2dC, nChunks, fineBase, cursorF,
                                            blockOffC, 1);
            kC_bin1<<<nChunks, 512, 0, stream>>>(rows, cols, value, nnz, M, S, d,
                                                 blockOffC, pairs1);
            kD_bin2<<<nChunks, 1024, 0, stream>>>(pairs1, nnz, cursorF, pairs2);
            k_spmm7<<<NBF, SP_T, smem, stream>>>(pairs2, fineBase, weight, bias, out, d, n);
        } else {
            kB_off<<<1, 1024, 0, stream>>>(gcnt, hist2dC, nChunks, fineBase, cursorF,
                                           blockOffC, 0);
            k_bin_direct<<<nChunks, 1024, 0, stream>>>(rows, cols, value, nnz, M, S, d,
                                                       cursorF, pairs1);
            k_spmm7<<<NBF, SP_T, smem, stream>>>(pairs1, fineBase, weight, bias, out, d, n);
        }
    } else {
        k_ghist<<<256, 512, 0, stream>>>(rows, nnz, M, S, gcnt);
        kB_off<<<1, 1024, 0, stream>>>(gcnt, hist2dC, nChunks, fineBase, cursorF,
                                       blockOffC, 0);
        k_bin_direct<<<nChunks, 1024, 0, stream>>>(rows, cols, value, nnz, M, S, d,
                                                   cursorF, pairs3);
        k_spmm7<<<NBF, SP_T, smem, stream>>>(pairs3, fineBase, weight, bias, out, d, n);
    }
}

// Round 5
// 195.601 us; speedup vs baseline: 7.3204x; 7.3204x over previous
//
#include <hip/hip_runtime.h>

// out[r,f] = bias[f] + sum_{i: rows[i]==r} value[i] * weight[cols[i], f]
// R12 pipeline (4 kernels): global fine histogram (k_ghist) -> scan (kB_off)
// -> single-pass fine bin with global cursor atomics (k_bin_direct) ->
// per-bucket LDS sort + register-FMA consumer (k_spmm5).
// R9/R11 post-mortem: per-element LDS atomic accumulate = 256M lane-level
// RMWs; LDS atomics retire ~1 lane/~3cyc/CU (measured: both CAS and
// ds_add_f32 land at ~1310us) -> 20x too slow. Sort-based consumer (60us)
// restored. The kC+kD two-pass atomic-free ordering was also pointless:
// k_spmm5 sorts each chunk by row, so within-bucket order is irrelevant ->
// k_bin_direct (one pass, cursorF global atomics) saves 2 histogram passes
// (~4M LDS lane-atomics each, ~15-20us) + 64MB HBM traffic.
// R13: identical resubmit — R12's bench was an infra failure (container
// failed twice; kernel never executed).
//
// pair pack (u64): val[63:32] | fine[29:20] | lr[19:13] | col[12:0]

#define NBF 1024
#define DMAX 128     // lr 7 bits => d <= 128 (n <= 131072)
#define CH 4096      // binning chunk
#define CC 1536      // consumer sort chunk
#define SP_T 512

__global__ void k_zero1024(int* __restrict__ p) { p[threadIdx.x] = 0; }

// Grid-stride fine histogram: LDS hist per block, global atomic merge.
__global__ void k_ghist(const int* __restrict__ rows, int nnz, unsigned M, int S,
                        int* __restrict__ gcnt) {
    __shared__ int h[NBF];
    int t = threadIdx.x;
    for (int i = t; i < NBF; i += blockDim.x) h[i] = 0;
    __syncthreads();
    for (int i = blockIdx.x * blockDim.x + t; i < nnz; i += gridDim.x * blockDim.x) {
        unsigned r = (unsigned)rows[i];
        int f = (int)(((unsigned long long)r * M) >> S);
        atomicAdd(&h[f], 1);
    }
    __syncthreads();
    for (int i = t; i < NBF; i += blockDim.x)
        if (h[i]) atomicAdd(&gcnt[i], h[i]);
}

// Scan gcnt -> fineBase + cursorF (doOff path retained but unused at 1 block).
__global__ __launch_bounds__(1024) void kB_off(const int* __restrict__ gcnt,
        const int* __restrict__ hist2dC, int nChunks, int* __restrict__ fineBase,
        int* __restrict__ cursorF, int* __restrict__ blockOffC, int doOff) {
    __shared__ int sE[NBF];
    __shared__ int wsum[16];
    __shared__ int totalSh;
    int t = threadIdx.x, lane = t & 63, wv = t >> 6;
    int v = gcnt[t];
    int x = v;
#pragma unroll
    for (int off = 1; off < 64; off <<= 1) {
        int y = __shfl_up(x, off, 64);
        if (lane >= off) x += y;
    }
    if (lane == 63) wsum[wv] = x;
    __syncthreads();
    if (t < 16) {
        int s = wsum[t], xs = s;
#pragma unroll
        for (int off = 1; off < 16; off <<= 1) {
            int y = __shfl_up(xs, off, 16);
            if (t >= off) xs += y;
        }
        wsum[t] = xs - s;
    }
    __syncthreads();
    int incl = x + wsum[wv], excl = incl - v;
    sE[t] = excl;
    if (blockIdx.x == 0) {
        fineBase[t] = excl;
        cursorF[t] = excl;
        if (t == NBF - 1) fineBase[NBF] = incl;
    }
    __syncthreads();
    if (!doOff) return;
    int c = blockIdx.x;
    int carry = sE[c << 4];
    for (int b2 = 0; b2 < nChunks; b2 += 1024) {
        int idx = b2 + t;
        int hv = (idx < nChunks) ? hist2dC[(idx << 6) + c] : 0;
        int hx = hv;
#pragma unroll
        for (int off = 1; off < 64; off <<= 1) {
            int y = __shfl_up(hx, off, 64);
            if (lane >= off) hx += y;
        }
        if (lane == 63) wsum[wv] = hx;
        __syncthreads();
        if (t < 16) {
            int s = wsum[t], xs = s;
#pragma unroll
            for (int off = 1; off < 16; off <<= 1) {
                int y = __shfl_up(xs, off, 16);
                if (t >= off) xs += y;
            }
            wsum[t] = xs - s;
        }
        __syncthreads();
        int hincl = hx + wsum[wv];
        if (idx < nChunks) blockOffC[(idx << 6) + c] = carry + hincl - hv;
        if (t == 1023) totalSh = hincl;
        __syncthreads();
        carry += totalSh;
    }
}

// Single-pass fine bin: per-chunk LDS hist + scan, one global atomicAdd per
// nonzero (block,bin) to reserve space, staged scatter for coalesced writes.
__global__ __launch_bounds__(1024) void k_bin_direct(const int* __restrict__ rows,
        const int* __restrict__ cols, const float* __restrict__ vals, int nnz,
        unsigned M, int S, int d, int* __restrict__ cursorF,
        unsigned long long* __restrict__ pairs1) {
    __shared__ unsigned long long stage[CH];
    __shared__ int histF[NBF], scF[NBF], adjF[NBF];
    __shared__ int wsum[16];
    int t = threadIdx.x, lane = t & 63, wv = t >> 6;
    long long base = (long long)blockIdx.x * CH;
    int count = (int)min((long long)CH, (long long)nnz - base);
    histF[t] = 0;
    __syncthreads();
    int f4[4], rk4[4];
    unsigned long long pk4[4];
#pragma unroll
    for (int k = 0; k < 4; ++k) {
        int i = t + (k << 10);
        f4[k] = -1;
        if (i < count) {
            unsigned r = (unsigned)rows[base + i];
            int c = cols[base + i];
            float vv = vals[base + i];
            int f = (int)(((unsigned long long)r * M) >> S);
            int lr = (int)r - f * d;
            f4[k] = f;
            rk4[k] = atomicAdd(&histF[f], 1);
            pk4[k] = ((unsigned long long)__float_as_uint(vv) << 32) |
                     ((unsigned)f << 20) | ((unsigned)lr << 13) | (unsigned)c;
        }
    }
    __syncthreads();
    int v = histF[t], x = v;
#pragma unroll
    for (int off = 1; off < 64; off <<= 1) {
        int y = __shfl_up(x, off, 64);
        if (lane >= off) x += y;
    }
    if (lane == 63) wsum[wv] = x;
    __syncthreads();
    if (t < 16) {
        int s = wsum[t], xs = s;
#pragma unroll
        for (int off = 1; off < 16; off <<= 1) {
            int y = __shfl_up(xs, off, 16);
            if (t >= off) xs += y;
        }
        wsum[t] = xs - s;
    }
    __syncthreads();
    int incl = x + wsum[wv];
    scF[t] = incl;
    if (v > 0) {
        int g = atomicAdd(&cursorF[t], v);
        adjF[t] = g - (incl - v);
    }
    __syncthreads();
#pragma unroll
    for (int k = 0; k < 4; ++k)
        if (f4[k] >= 0) stage[(scF[f4[k]] - histF[f4[k]]) + rk4[k]] = pk4[k];
    __syncthreads();
    for (int i = t; i < count; i += 1024) {
        unsigned long long p = stage[i];
        int f = (int)((p >> 20) & 1023);
        pairs1[adjF[f] + i] = p;
    }
}

// Consumer: one block per fine bucket, 38.4 KB LDS => 4 blocks/CU. Sort chunk
// by local row (int LDS atomics + shfl scan), then 16-lane groups walk whole
// rows with 4-wide batched weight loads (4 independent dwordx4 in flight).
__global__ __launch_bounds__(SP_T, 8) void k_spmm5(
        const unsigned long long* __restrict__ pairs, const int* __restrict__ fineBase,
        const float* __restrict__ weight, const float* __restrict__ bias,
        float* __restrict__ out, int d, int n) {
    __shared__ unsigned long long stage[CC];   // 12 KB
    __shared__ int histR[DMAX], scR[DMAX];     // 1 KB
    extern __shared__ float acc[];             // d*64 floats (25 KB @ d=98)
    int b = blockIdx.x, t = threadIdx.x;
    int row0 = b * d;
    if (row0 >= n) return;
    int nrows = min(d, n - row0);
    int start = fineBase[b], end = fineBase[b + 1];

    for (int i = t; i < (nrows << 6); i += SP_T) acc[i] = 0.0f;

    int g = t >> 4, fq = t & 15;
    for (int cb = start; cb < end; cb += CC) {
        int cnt = min(CC, end - cb);
        if (t < DMAX) histR[t] = 0;
        __syncthreads();
        int lr3[3], rk3[3];
        unsigned long long pk3[3];
#pragma unroll
        for (int k = 0; k < 3; ++k) {
            int i = t + (k << 9);
            lr3[k] = -1;
            if (i < cnt) {
                unsigned long long p = pairs[cb + i];
                int lr = (int)((p >> 13) & 127);
                lr3[k] = lr;
                rk3[k] = atomicAdd(&histR[lr], 1);
                pk3[k] = p;
            }
        }
        __syncthreads();
        if (t < DMAX) {
            int v = histR[t], x = v;
            int lane = t & 63;
#pragma unroll
            for (int off = 1; off < 64; off <<= 1) {
                int y = __shfl_up(x, off, 64);
                if (lane >= off) x += y;
            }
            scR[t] = x;
        }
        __syncthreads();
        if (t >= 64 && t < DMAX) scR[t] += scR[63];
        __syncthreads();
#pragma unroll
        for (int k = 0; k < 3; ++k)
            if (lr3[k] >= 0) stage[(scR[lr3[k]] - histR[lr3[k]]) + rk3[k]] = pk3[k];
        __syncthreads();

        for (int r = g; r < nrows; r += 32) {
            int e = scR[r], s = e - histR[r];
            if (s >= e) continue;
            float4 a = {0.0f, 0.0f, 0.0f, 0.0f};
            int j = s;
            for (; j + 4 <= e; j += 4) {
                unsigned long long p0 = stage[j + 0];
                unsigned long long p1 = stage[j + 1];
                unsigned long long p2 = stage[j + 2];
                unsigned long long p3 = stage[j + 3];
                const float4 w0 = *(const float4*)(weight + (((int)(p0 & 8191)) << 6) + (fq << 2));
                const float4 w1 = *(const float4*)(weight + (((int)(p1 & 8191)) << 6) + (fq << 2));
                const float4 w2 = *(const float4*)(weight + (((int)(p2 & 8191)) << 6) + (fq << 2));
                const float4 w3 = *(const float4*)(weight + (((int)(p3 & 8191)) << 6) + (fq << 2));
                float v0 = __uint_as_float((unsigned)(p0 >> 32));
                float v1 = __uint_as_float((unsigned)(p1 >> 32));
                float v2 = __uint_as_float((unsigned)(p2 >> 32));
                float v3 = __uint_as_float((unsigned)(p3 >> 32));
                a.x = fmaf(v0, w0.x, a.x); a.y = fmaf(v0, w0.y, a.y);
                a.z = fmaf(v0, w0.z, a.z); a.w = fmaf(v0, w0.w, a.w);
                a.x = fmaf(v1, w1.x, a.x); a.y = fmaf(v1, w1.y, a.y);
                a.z = fmaf(v1, w1.z, a.z); a.w = fmaf(v1, w1.w, a.w);
                a.x = fmaf(v2, w2.x, a.x); a.y = fmaf(v2, w2.y, a.y);
                a.z = fmaf(v2, w2.z, a.z); a.w = fmaf(v2, w2.w, a.w);
                a.x = fmaf(v3, w3.x, a.x); a.y = fmaf(v3, w3.y, a.y);
                a.z = fmaf(v3, w3.z, a.z); a.w = fmaf(v3, w3.w, a.w);
            }
            for (; j < e; ++j) {
                unsigned long long p = stage[j];
                float vv = __uint_as_float((unsigned)(p >> 32));
                const float4 w = *(const float4*)(weight + (((int)(p & 8191)) << 6) + (fq << 2));
                a.x = fmaf(vv, w.x, a.x); a.y = fmaf(vv, w.y, a.y);
                a.z = fmaf(vv, w.z, a.z); a.w = fmaf(vv, w.w, a.w);
            }
            float4* ap = (float4*)&acc[(r << 6) + (fq << 2)];
            float4 o = *ap;
            o.x += a.x; o.y += a.y; o.z += a.z; o.w += a.w;
            *ap = o;
        }
        __syncthreads();
    }

    for (int i = t; i < (nrows << 6); i += SP_T)
        out[((long long)row0 << 6) + i] = acc[i] + bias[i & 63];
}

extern "C" void kernel_launch(void* const* d_in, const int* in_sizes, int n_in,
                              void* d_out, int out_size, void* d_ws, size_t ws_size,
                              hipStream_t stream) {
    const int*   index  = (const int*)d_in[0];
    const float* value  = (const float*)d_in[1];
    const float* weight = (const float*)d_in[3];
    const float* bias   = (const float*)d_in[4];
    float*       out    = (float*)d_out;

    int nnz = in_sizes[0] / 2;
    int n   = out_size / 64;
    const int* rows = index;
    const int* cols = index + nnz;

    int d = (n + NBF - 1) / NBF;  // 98 for n=100000 (<= DMAX)
    unsigned M = 0;
    int S = 0;
    for (S = 20; S <= 40; ++S) {
        unsigned long long m = ((1ull << S) + (unsigned)d - 1) / (unsigned)d;
        unsigned long long e = m * (unsigned long long)d - (1ull << S);
        if (m <= 0xffffffffull && e * (unsigned long long)(n > 0 ? n - 1 : 0) < (1ull << S)) {
            M = (unsigned)m;
            break;
        }
    }

    int nChunks = (nnz + CH - 1) / CH;
    char* ws = (char*)d_ws;
    int* fineBase = (int*)ws;                 // 8 KB reserved
    int* cursorF  = (int*)(ws + (8 << 10));   // 4 KB
    int* gcnt     = (int*)(ws + (12 << 10));  // 4 KB
    size_t offC = 64 << 10;                   // legacy layout preserved
    size_t szC  = (((size_t)nChunks * 64 * 4) + 255) & ~(size_t)255;
    size_t offO = offC + szC;
    size_t offF = offO + szC;
    size_t szF  = (((size_t)nChunks * NBF * 4) + 255) & ~(size_t)255;
    size_t offP1 = offF + szF;
    size_t szP   = (((size_t)nnz * 8) + 255) & ~(size_t)255;
    int* hist2dC   = (int*)(ws + offC);
    int* blockOffC = (int*)(ws + offO);
    unsigned long long* pairs1 = (unsigned long long*)(ws + offP1);
    unsigned long long* pairs3 = (unsigned long long*)(ws + offC);  // small-ws overlay

    bool fits = ws_size >= offP1 + szP;
    unsigned long long* pairs = fits ? pairs1 : pairs3;

    k_zero1024<<<1, 1024, 0, stream>>>(gcnt);
    size_t smem = (size_t)d * 64 * sizeof(float);
    k_ghist<<<256, 512, 0, stream>>>(rows, nnz, M, S, gcnt);
    kB_off<<<1, 1024, 0, stream>>>(gcnt, hist2dC, nChunks, fineBase, cursorF,
                                   blockOffC, 0);
    k_bin_direct<<<nChunks, 1024, 0, stream>>>(rows, cols, value, nnz, M, S, d,
                                               cursorF, pairs);
    k_spmm5<<<NBF, SP_T, smem, stream>>>(pairs, fineBase, weight, bias, out, d, n);
}

// Round 6
// 185.050 us; speedup vs baseline: 7.7377x; 1.0570x over previous
//
#include <hip/hip_runtime.h>

// out[r,f] = bias[f] + sum_{i: rows[i]==r} value[i] * weight[cols[i], f]
// R14 pipeline (3 kernels): k_init (cursor=f*slots) -> k_bin_fixed (per-chunk
// LDS hist+scan, global cursor atomics, FIXED-STRIDE bucket slots + spill) ->
// k_spmm8 (double-buffered sort/consume overlap, 4 blocks/CU).
// History: R9/R11: per-element LDS atomic accumulate = 256M lane RMWs at
// ~3cyc/lane -> 1310us, dead end. R13: exact-bucket-base front end (ghist+
// scan) cost ~30us + 2 launches for information fixed-stride allocation gets
// for free on uniform rows (slots ~= mean+16sigma; spill path for the rest).
// Consumer: sort(k+1) ranking overlaps consume(k) -- LDS-atomic pipe and
// L2-gather/VALU pipes are independent (m114). acc row r owned by group r&31
// so overlapped consume never races.
//
// pair pack (u64): val[63:32] | fine[29:20] | lr[19:13] | col[12:0]

#define NBF 1024
#define DMAX 128     // lr 7 bits => d <= 128 (n <= 131072)
#define CH 4096      // binning chunk
#define CC2 768      // consumer sort chunk (2 buffers)
#define SP_T 512

__device__ __forceinline__ void ds_fadd(float* p, float v) {
    unsigned a = (unsigned)(unsigned long long)p;  // LDS byte offset
    asm volatile("ds_add_f32 %0, %1" :: "v"(a), "v"(v) : "memory");
}

__global__ void k_init(int* __restrict__ cursorF, int* __restrict__ ovfCnt, int slots) {
    cursorF[threadIdx.x] = threadIdx.x * slots;
    if (threadIdx.x == 0) *ovfCnt = 0;
}

// Single-pass fine bin into fixed-stride bucket slots. Per-chunk LDS hist +
// scan + stage for coalesced-ish writes; one global atomicAdd per (block,bin)
// reserves space; element lands at dest if within its bucket's slot window,
// else spills to ovf (statistically never for uniform rows).
__global__ __launch_bounds__(1024) void k_bin_fixed(const int* __restrict__ rows,
        const int* __restrict__ cols, const float* __restrict__ vals, int nnz,
        unsigned M, int S, int d, int slots, int* __restrict__ cursorF,
        unsigned long long* __restrict__ pairs1, int* __restrict__ ovfCnt,
        unsigned long long* __restrict__ ovf) {
    __shared__ unsigned long long stage[CH];
    __shared__ int histF[NBF], scF[NBF], adjF[NBF];
    __shared__ int wsum[16];
    int t = threadIdx.x, lane = t & 63, wv = t >> 6;
    long long base = (long long)blockIdx.x * CH;
    int count = (int)min((long long)CH, (long long)nnz - base);
    histF[t] = 0;
    __syncthreads();
    int f4[4], rk4[4];
    unsigned long long pk4[4];
#pragma unroll
    for (int k = 0; k < 4; ++k) {
        int i = t + (k << 10);
        f4[k] = -1;
        if (i < count) {
            unsigned r = (unsigned)rows[base + i];
            int c = cols[base + i];
            float vv = vals[base + i];
            int f = (int)(((unsigned long long)r * M) >> S);
            int lr = (int)r - f * d;
            f4[k] = f;
            rk4[k] = atomicAdd(&histF[f], 1);
            pk4[k] = ((unsigned long long)__float_as_uint(vv) << 32) |
                     ((unsigned)f << 20) | ((unsigned)lr << 13) | (unsigned)c;
        }
    }
    __syncthreads();
    int v = histF[t], x = v;
#pragma unroll
    for (int off = 1; off < 64; off <<= 1) {
        int y = __shfl_up(x, off, 64);
        if (lane >= off) x += y;
    }
    if (lane == 63) wsum[wv] = x;
    __syncthreads();
    if (t < 16) {
        int s = wsum[t], xs = s;
#pragma unroll
        for (int off = 1; off < 16; off <<= 1) {
            int y = __shfl_up(xs, off, 16);
            if (t >= off) xs += y;
        }
        wsum[t] = xs - s;
    }
    __syncthreads();
    int incl = x + wsum[wv];
    scF[t] = incl;
    if (v > 0) {
        int g = atomicAdd(&cursorF[t], v);
        adjF[t] = g - (incl - v);
    }
    __syncthreads();
#pragma unroll
    for (int k = 0; k < 4; ++k)
        if (f4[k] >= 0) stage[(scF[f4[k]] - histF[f4[k]]) + rk4[k]] = pk4[k];
    __syncthreads();
    for (int i = t; i < count; i += 1024) {
        unsigned long long p = stage[i];
        int f = (int)((p >> 20) & 1023);
        int dest = adjF[f] + i;
        if (dest < (f + 1) * slots) pairs1[dest] = p;
        else ovf[atomicAdd(ovfCnt, 1)] = p;
    }
}

// Consumer v4: one block per bucket, double-buffered. Per chunk, 3 barriers:
//   region1: {rank chunk c+1 into histR[nxt] (LDS atomics, global loads)
//             || consume chunk c from stg[cur] (L2 gather + FMA)}
//   region2: wave0 scans histR[nxt] -> scR[nxt]
//   region3: scatter chunk c+1 -> stg[nxt]; zero histR[cur] for c+2
// LDS: 2*768*8 + 2*2*128*4 + d*64*4 = 39.4 KB @ d=98 -> 4 blocks/CU (32 wv).
// acc row r is written only by group r&31 -> no cross-iteration races.
__global__ __launch_bounds__(SP_T, 8) void k_spmm8(
        const unsigned long long* __restrict__ pairs, const int* __restrict__ cursorF,
        const int* __restrict__ ovfCnt, const unsigned long long* __restrict__ ovf,
        const float* __restrict__ weight, const float* __restrict__ bias,
        float* __restrict__ out, int d, int n, int slots) {
    __shared__ unsigned long long stg[2][CC2];   // 12 KB
    __shared__ int histR[2][DMAX], scR[2][DMAX]; // 2 KB
    extern __shared__ float acc[];               // d*64 floats
    int b = blockIdx.x, t = threadIdx.x;
    int row0 = b * d;
    if (row0 >= n) return;
    int nrows = min(d, n - row0);
    long long sbase = (long long)b * slots;
    int cnt = cursorF[b] - (int)sbase;
    if (cnt > slots) cnt = slots;
    if (cnt < 0) cnt = 0;

    for (int i = t; i < (nrows << 6); i += SP_T) acc[i] = 0.0f;
    int g = t >> 4, fq = t & 15;
    int nt = (cnt + CC2 - 1) / CC2;

    int lr2[2], rk2[2];
    unsigned long long pk2[2];

    // prologue: zero both hists; rank + scan + scatter chunk 0 into buf 0
    if (t < DMAX) { histR[0][t] = 0; histR[1][t] = 0; }
    __syncthreads();
    if (nt > 0) {
        int c0 = min(CC2, cnt);
#pragma unroll
        for (int k = 0; k < 2; ++k) {
            int i = t + (k << 9);
            lr2[k] = -1;
            if (i < c0) {
                unsigned long long p = pairs[sbase + i];
                int lr = (int)((p >> 13) & 127);
                lr2[k] = lr; rk2[k] = atomicAdd(&histR[0][lr], 1); pk2[k] = p;
            }
        }
        __syncthreads();
        if (t < 64) {
            int v0 = histR[0][t], v1 = histR[0][t + 64];
            int x0 = v0;
#pragma unroll
            for (int off = 1; off < 64; off <<= 1) {
                int y = __shfl_up(x0, off, 64);
                if (t >= off) x0 += y;
            }
            int tot = __shfl(x0, 63, 64);
            int x1 = v1;
#pragma unroll
            for (int off = 1; off < 64; off <<= 1) {
                int y = __shfl_up(x1, off, 64);
                if (t >= off) x1 += y;
            }
            x1 += tot;
            scR[0][t] = x0; scR[0][t + 64] = x1;
        }
        __syncthreads();
#pragma unroll
        for (int k = 0; k < 2; ++k)
            if (lr2[k] >= 0) stg[0][scR[0][lr2[k]] - histR[0][lr2[k]] + rk2[k]] = pk2[k];
        __syncthreads();
    }

    for (int c = 0; c < nt; ++c) {
        int cur = c & 1, nxt = cur ^ 1;
        bool more = (c + 1 < nt);
        // region1: rank next chunk || consume current
        if (more) {
            int nb = (c + 1) * CC2;
            int ncnt = min(CC2, cnt - nb);
#pragma unroll
            for (int k = 0; k < 2; ++k) {
                int i = t + (k << 9);
                lr2[k] = -1;
                if (i < ncnt) {
                    unsigned long long p = pairs[sbase + nb + i];
                    int lr = (int)((p >> 13) & 127);
                    lr2[k] = lr; rk2[k] = atomicAdd(&histR[nxt][lr], 1); pk2[k] = p;
                }
            }
        } else {
            lr2[0] = lr2[1] = -1;
        }
        for (int r = g; r < nrows; r += 32) {
            int e = scR[cur][r], s = e - histR[cur][r];
            if (s >= e) continue;
            float4 a = {0.0f, 0.0f, 0.0f, 0.0f};
            int j = s;
            for (; j + 4 <= e; j += 4) {
                unsigned long long p0 = stg[cur][j + 0];
                unsigned long long p1 = stg[cur][j + 1];
                unsigned long long p2 = stg[cur][j + 2];
                unsigned long long p3 = stg[cur][j + 3];
                const float4 w0 = *(const float4*)(weight + (((int)(p0 & 8191)) << 6) + (fq << 2));
                const float4 w1 = *(const float4*)(weight + (((int)(p1 & 8191)) << 6) + (fq << 2));
                const float4 w2 = *(const float4*)(weight + (((int)(p2 & 8191)) << 6) + (fq << 2));
                const float4 w3 = *(const float4*)(weight + (((int)(p3 & 8191)) << 6) + (fq << 2));
                float v0 = __uint_as_float((unsigned)(p0 >> 32));
                float v1 = __uint_as_float((unsigned)(p1 >> 32));
                float v2 = __uint_as_float((unsigned)(p2 >> 32));
                float v3 = __uint_as_float((unsigned)(p3 >> 32));
                a.x = fmaf(v0, w0.x, a.x); a.y = fmaf(v0, w0.y, a.y);
                a.z = fmaf(v0, w0.z, a.z); a.w = fmaf(v0, w0.w, a.w);
                a.x = fmaf(v1, w1.x, a.x); a.y = fmaf(v1, w1.y, a.y);
                a.z = fmaf(v1, w1.z, a.z); a.w = fmaf(v1, w1.w, a.w);
                a.x = fmaf(v2, w2.x, a.x); a.y = fmaf(v2, w2.y, a.y);
                a.z = fmaf(v2, w2.z, a.z); a.w = fmaf(v2, w2.w, a.w);
                a.x = fmaf(v3, w3.x, a.x); a.y = fmaf(v3, w3.y, a.y);
                a.z = fmaf(v3, w3.z, a.z); a.w = fmaf(v3, w3.w, a.w);
            }
            for (; j < e; ++j) {
                unsigned long long p = stg[cur][j];
                float vv = __uint_as_float((unsigned)(p >> 32));
                const float4 w = *(const float4*)(weight + (((int)(p & 8191)) << 6) + (fq << 2));
                a.x = fmaf(vv, w.x, a.x); a.y = fmaf(vv, w.y, a.y);
                a.z = fmaf(vv, w.z, a.z); a.w = fmaf(vv, w.w, a.w);
            }
            float4* ap = (float4*)&acc[(r << 6) + (fq << 2)];
            float4 o = *ap;
            o.x += a.x; o.y += a.y; o.z += a.z; o.w += a.w;
            *ap = o;
        }
        __syncthreads();
        // region2: scan next hist (wave 0)
        if (more && t < 64) {
            int v0 = histR[nxt][t], v1 = histR[nxt][t + 64];
            int x0 = v0;
#pragma unroll
            for (int off = 1; off < 64; off <<= 1) {
                int y = __shfl_up(x0, off, 64);
                if (t >= off) x0 += y;
            }
            int tot = __shfl(x0, 63, 64);
            int x1 = v1;
#pragma unroll
            for (int off = 1; off < 64; off <<= 1) {
                int y = __shfl_up(x1, off, 64);
                if (t >= off) x1 += y;
            }
            x1 += tot;
            scR[nxt][t] = x0; scR[nxt][t + 64] = x1;
        }
        __syncthreads();
        // region3: scatter next chunk; pre-zero cur hist for c+2
#pragma unroll
        for (int k = 0; k < 2; ++k)
            if (lr2[k] >= 0) stg[nxt][scR[nxt][lr2[k]] - histR[nxt][lr2[k]] + rk2[k]] = pk2[k];
        if (t < DMAX) histR[cur][t] = 0;
        __syncthreads();
    }

    // overflow (spilled pairs): rare/never for uniform rows; atomic LDS adds.
    int oc = *ovfCnt;
    if (oc > 0) {
        __syncthreads();
        for (int i = g; i < oc; i += (SP_T >> 4)) {
            unsigned long long p = ovf[i];
            if ((int)((p >> 20) & 1023) == b) {
                int lr = (int)((p >> 13) & 127);
                int cc = (int)(p & 8191);
                float vv = __uint_as_float((unsigned)(p >> 32));
                const float4 w = *(const float4*)(weight + (cc << 6) + (fq << 2));
                float* ap = &acc[(lr << 6) + (fq << 2)];
                ds_fadd(ap + 0, vv * w.x); ds_fadd(ap + 1, vv * w.y);
                ds_fadd(ap + 2, vv * w.z); ds_fadd(ap + 3, vv * w.w);
            }
        }
        asm volatile("s_waitcnt lgkmcnt(0)" ::: "memory");
        __builtin_amdgcn_sched_barrier(0);
    }
    __syncthreads();

    for (int i = t; i < (nrows << 6); i += SP_T)
        out[((long long)row0 << 6) + i] = acc[i] + bias[i & 63];
}

extern "C" void kernel_launch(void* const* d_in, const int* in_sizes, int n_in,
                              void* d_out, int out_size, void* d_ws, size_t ws_size,
                              hipStream_t stream) {
    const int*   index  = (const int*)d_in[0];
    const float* value  = (const float*)d_in[1];
    const float* weight = (const float*)d_in[3];
    const float* bias   = (const float*)d_in[4];
    float*       out    = (float*)d_out;

    int nnz = in_sizes[0] / 2;
    int n   = out_size / 64;
    const int* rows = index;
    const int* cols = index + nnz;

    int d = (n + NBF - 1) / NBF;  // 98 for n=100000 (<= DMAX)
    unsigned M = 0;
    int S = 0;
    for (S = 20; S <= 40; ++S) {
        unsigned long long m = ((1ull << S) + (unsigned)d - 1) / (unsigned)d;
        unsigned long long e = m * (unsigned long long)d - (1ull << S);
        if (m <= 0xffffffffull && e * (unsigned long long)(n > 0 ? n - 1 : 0) < (1ull << S)) {
            M = (unsigned)m;
            break;
        }
    }

    int nChunks = (nnz + CH - 1) / CH;
    char* ws = (char*)d_ws;
    int* cursorF = (int*)ws;                  // 4 KB
    int* ovfCnt  = (int*)(ws + 4096);
    unsigned long long* pairsS = (unsigned long long*)(ws + 65536);

    size_t szOvf = (((size_t)nnz * 8) + 255) & ~(size_t)255;
    size_t availS = (ws_size > 65536 + szOvf) ? (ws_size - 65536 - szOvf) : 0;
    long long slotsL = (long long)(availS / ((size_t)NBF * 8));
    int slots = (int)(slotsL > 6144 ? 6144 : slotsL);
    if (slots > 64) slots &= ~63;
    if (slots < 1) slots = 1;
    unsigned long long* ovf = (unsigned long long*)(ws + 65536 + (size_t)slots * NBF * 8);

    k_init<<<1, 1024, 0, stream>>>(cursorF, ovfCnt, slots);
    k_bin_fixed<<<nChunks, 1024, 0, stream>>>(rows, cols, value, nnz, M, S, d, slots,
                                              cursorF, pairsS, ovfCnt, ovf);
    size_t smem = (size_t)d * 64 * sizeof(float);
    k_spmm8<<<NBF, SP_T, smem, stream>>>(pairsS, cursorF, ovfCnt, ovf, weight, bias,
                                         out, d, n, slots);
}